// Round 3
// baseline (4259.227 us; speedup 1.0000x reference)
//
#include <hip/hip_runtime.h>
#include <math.h>

#define NN 4096
#define FF 256
#define RR 8
#define KSPLIT 2
#define KHALF (NN / KSPLIT)
#define BQ 16384

// ---------------------------------------------------------------------------
// Kernel 1: G[r] = H @ W[r]^T   (M=4096, N=256, K=256), batched r
// grid (4, 64, 8) = 2048 blocks; 64x64 tile, 4x4/thread, BK=32, reg prefetch.
// ---------------------------------------------------------------------------
__global__ __launch_bounds__(256) void gemm_g(const float* __restrict__ H,
                                              const float* __restrict__ W,
                                              float* __restrict__ G) {
    __shared__ float Hs[32][68];
    __shared__ float Ws[32][68];

    const int tid = threadIdx.x;
    const int r   = blockIdx.z;
    const int o0  = blockIdx.x * 64;
    const int m0  = blockIdx.y * 64;
    const int tx  = tid & 15;
    const int ty  = tid >> 4;

    const float* __restrict__ Wr = W + (size_t)r * FF * FF;

    const int lr = tid >> 2;
    const int lc = (tid & 3) * 8;

    float acc[4][4];
#pragma unroll
    for (int i = 0; i < 4; ++i)
#pragma unroll
        for (int j = 0; j < 4; ++j) acc[i][j] = 0.0f;

    float4 h0 = *(const float4*)&H[(size_t)(m0 + lr) * FF + lc];
    float4 h1 = *(const float4*)&H[(size_t)(m0 + lr) * FF + lc + 4];
    float4 w0 = *(const float4*)&Wr[(size_t)(o0 + lr) * FF + lc];
    float4 w1 = *(const float4*)&Wr[(size_t)(o0 + lr) * FF + lc + 4];

    for (int fb = 0; fb < FF; fb += 32) {
        __syncthreads();
        Hs[lc + 0][lr] = h0.x;  Hs[lc + 1][lr] = h0.y;
        Hs[lc + 2][lr] = h0.z;  Hs[lc + 3][lr] = h0.w;
        Hs[lc + 4][lr] = h1.x;  Hs[lc + 5][lr] = h1.y;
        Hs[lc + 6][lr] = h1.z;  Hs[lc + 7][lr] = h1.w;
        Ws[lc + 0][lr] = w0.x;  Ws[lc + 1][lr] = w0.y;
        Ws[lc + 2][lr] = w0.z;  Ws[lc + 3][lr] = w0.w;
        Ws[lc + 4][lr] = w1.x;  Ws[lc + 5][lr] = w1.y;
        Ws[lc + 6][lr] = w1.z;  Ws[lc + 7][lr] = w1.w;
        __syncthreads();

        if (fb + 32 < FF) {
            h0 = *(const float4*)&H[(size_t)(m0 + lr) * FF + fb + 32 + lc];
            h1 = *(const float4*)&H[(size_t)(m0 + lr) * FF + fb + 32 + lc + 4];
            w0 = *(const float4*)&Wr[(size_t)(o0 + lr) * FF + fb + 32 + lc];
            w1 = *(const float4*)&Wr[(size_t)(o0 + lr) * FF + fb + 32 + lc + 4];
        }

#pragma unroll
        for (int k = 0; k < 32; ++k) {
            float4 hv = *(const float4*)&Hs[k][ty * 4];
            float4 wv = *(const float4*)&Ws[k][tx * 4];
            float a[4] = {hv.x, hv.y, hv.z, hv.w};
            float b[4] = {wv.x, wv.y, wv.z, wv.w};
#pragma unroll
            for (int i = 0; i < 4; ++i)
#pragma unroll
                for (int j = 0; j < 4; ++j) acc[i][j] += a[i] * b[j];
        }
    }

    float* __restrict__ Gp = G + ((size_t)r * NN + m0) * FF + o0;
#pragma unroll
    for (int i = 0; i < 4; ++i) {
        float4 v = {acc[i][0], acc[i][1], acc[i][2], acc[i][3]};
        *(float4*)&Gp[(size_t)(ty * 4 + i) * FF + tx * 4] = v;
    }
}

// ---------------------------------------------------------------------------
// Kernel 2: P[z] = c[r] * (A[r][:, kslice] @ G[r][kslice, :]),  z = r*2+s
// grid (2, 32, 16) = 1024 blocks (4/CU); 128x128 tile, 8x8/thread, BK=32,
// register prefetch, conflict-free split fragments.
// ---------------------------------------------------------------------------
__global__ __launch_bounds__(256, 4) void gemm_ag(const float* __restrict__ A,
                                                  const float* __restrict__ G,
                                                  const float* __restrict__ c,
                                                  float* __restrict__ P) {
    __shared__ float As[32][132];   // [k][row], +4 pad
    __shared__ float Bs[32][128];   // [k][col]

    const int tid = threadIdx.x;
    const int z   = blockIdx.z;       // 0..15
    const int r   = z >> 1;
    const int s   = z & 1;
    const int kb0 = s * KHALF;
    const int n0  = blockIdx.y * 128;
    const int f0  = blockIdx.x * 128;

    const float* __restrict__ Ar = A + (size_t)r * NN * NN;
    const float* __restrict__ Gr = G + (size_t)r * NN * FF;

    const int tx = tid & 15;
    const int ty = tid >> 4;   // 0..15

    const int lar = tid >> 1;          // A row 0..127
    const int lac = (tid & 1) * 16;    // A k offset 0 or 16
    const int lbr = tid >> 5;          // B k-row 0..7 (+8j)
    const int lbc = (tid & 31) * 4;    // B col

    float acc[8][8];
#pragma unroll
    for (int i = 0; i < 8; ++i)
#pragma unroll
        for (int j = 0; j < 8; ++j) acc[i][j] = 0.0f;

    const size_t arow = (size_t)(n0 + lar) * NN;

    float4 pa[4], pb[4];
#pragma unroll
    for (int j = 0; j < 4; ++j)
        pa[j] = *(const float4*)&Ar[arow + kb0 + lac + j * 4];
#pragma unroll
    for (int j = 0; j < 4; ++j)
        pb[j] = *(const float4*)&Gr[(size_t)(kb0 + lbr + 8 * j) * FF + f0 + lbc];

    for (int kb = kb0; kb < kb0 + KHALF; kb += 32) {
        __syncthreads();
#pragma unroll
        for (int j = 0; j < 4; ++j) {
            As[lac + j * 4 + 0][lar] = pa[j].x;
            As[lac + j * 4 + 1][lar] = pa[j].y;
            As[lac + j * 4 + 2][lar] = pa[j].z;
            As[lac + j * 4 + 3][lar] = pa[j].w;
        }
#pragma unroll
        for (int j = 0; j < 4; ++j)
            *(float4*)&Bs[lbr + 8 * j][lbc] = pb[j];
        __syncthreads();

        if (kb + 32 < kb0 + KHALF) {
#pragma unroll
            for (int j = 0; j < 4; ++j)
                pa[j] = *(const float4*)&Ar[arow + kb + 32 + lac + j * 4];
#pragma unroll
            for (int j = 0; j < 4; ++j)
                pb[j] = *(const float4*)&Gr[(size_t)(kb + 32 + lbr + 8 * j) * FF + f0 + lbc];
        }

#pragma unroll
        for (int k = 0; k < 32; ++k) {
            float4 a0 = *(const float4*)&As[k][ty * 4];
            float4 a1 = *(const float4*)&As[k][64 + ty * 4];
            float4 b0 = *(const float4*)&Bs[k][tx * 4];
            float4 b1 = *(const float4*)&Bs[k][64 + tx * 4];
            float a[8] = {a0.x, a0.y, a0.z, a0.w, a1.x, a1.y, a1.z, a1.w};
            float b[8] = {b0.x, b0.y, b0.z, b0.w, b1.x, b1.y, b1.z, b1.w};
#pragma unroll
            for (int i = 0; i < 8; ++i)
#pragma unroll
                for (int j = 0; j < 8; ++j) acc[i][j] += a[i] * b[j];
        }
    }

    float* __restrict__ Pp = P + ((size_t)z * NN + n0) * FF + f0;
#pragma unroll
    for (int i = 0; i < 8; ++i) {
        const int row = (i < 4) ? (ty * 4 + i) : (64 + ty * 4 + (i - 4));
        const float cv = c[r * NN + n0 + row];
        float4 v0 = {acc[i][0] * cv, acc[i][1] * cv, acc[i][2] * cv, acc[i][3] * cv};
        float4 v1 = {acc[i][4] * cv, acc[i][5] * cv, acc[i][6] * cv, acc[i][7] * cv};
        *(float4*)&Pp[(size_t)row * FF + tx * 4]      = v0;
        *(float4*)&Pp[(size_t)row * FF + 64 + tx * 4] = v1;
    }
}

// ---------------------------------------------------------------------------
// Kernel 3: Hout = sum over 16 partial planes of P
// ---------------------------------------------------------------------------
__global__ __launch_bounds__(256) void reduce_p(const float* __restrict__ P,
                                                float* __restrict__ Hout) {
    const size_t idx = ((size_t)blockIdx.x * 256 + threadIdx.x) * 4;
    float4 s = *(const float4*)&P[idx];
#pragma unroll
    for (int z = 1; z < RR * KSPLIT; ++z) {
        float4 v = *(const float4*)&P[(size_t)z * NN * FF + idx];
        s.x += v.x; s.y += v.y; s.z += v.z; s.w += v.w;
    }
    *(float4*)&Hout[idx] = s;
}

// ---------------------------------------------------------------------------
// Kernel 4: score[b] = sigmoid( sum_f E1[b,f] * Mdiag[rel[b],f] * E2[b,f] )
// rel_mats are exactly diagonal => diagonal-only is numerically identical.
// ---------------------------------------------------------------------------
__global__ __launch_bounds__(256) void score_k(const float* __restrict__ H2,
                                               const float* __restrict__ relm,
                                               const int* __restrict__ e1,
                                               const int* __restrict__ rel,
                                               const int* __restrict__ e2,
                                               float* __restrict__ out) {
    const int wave = threadIdx.x >> 6;
    const int lane = threadIdx.x & 63;
    const int b = blockIdx.x * 4 + wave;
    if (b >= BQ) return;

    const int rr = rel[b];
    const float4* __restrict__ x = (const float4*)(H2 + (size_t)e1[b] * FF);
    const float4* __restrict__ y = (const float4*)(H2 + (size_t)e2[b] * FF);
    const float* __restrict__ M = relm + (size_t)rr * FF * FF;

    float4 xv = x[lane];
    float4 yv = y[lane];
    const int f = lane * 4;
    float s = xv.x * yv.x * M[(size_t)(f + 0) * (FF + 1)]
            + xv.y * yv.y * M[(size_t)(f + 1) * (FF + 1)]
            + xv.z * yv.z * M[(size_t)(f + 2) * (FF + 1)]
            + xv.w * yv.w * M[(size_t)(f + 3) * (FF + 1)];

#pragma unroll
    for (int off = 32; off > 0; off >>= 1) s += __shfl_down(s, off, 64);

    if (lane == 0) out[b] = 1.0f / (1.0f + expf(-s));
}

// ---------------------------------------------------------------------------
extern "C" void kernel_launch(void* const* d_in, const int* in_sizes, int n_in,
                              void* d_out, int out_size, void* d_ws, size_t ws_size,
                              hipStream_t stream) {
    const float* A    = (const float*)d_in[0];   // [R,N,N]
    const float* feat = (const float*)d_in[1];   // [N,F]
    const float* c    = (const float*)d_in[2];   // [R,N,1]
    const float* W1   = (const float*)d_in[3];   // [R,F,F]
    const float* W2   = (const float*)d_in[4];   // [R,F,F]
    const float* relm = (const float*)d_in[5];   // [R,F,F]
    const int*   e1   = (const int*)d_in[6];     // [B]
    const int*   rel  = (const int*)d_in[7];     // [B]
    const int*   e2   = (const int*)d_in[8];     // [B]
    float* out = (float*)d_out;                  // [B]

    float* G  = (float*)d_ws;                     // R*N*F        = 32 MB
    float* P  = G + (size_t)RR * NN * FF;         // 16*N*F       = 64 MB
    float* H1 = P + (size_t)RR * KSPLIT * NN * FF;// N*F          =  4 MB
    float* H2 = H1 + (size_t)NN * FF;             // N*F          =  4 MB

    dim3 gg(FF / 64, NN / 64, RR);        // (4, 64, 8)  = 2048
    dim3 ga(FF / 128, NN / 128, RR * KSPLIT); // (2, 32, 16) = 1024
    const int gr = (NN * FF / 4) / 256;   // 1024 blocks

    // Layer 1
    gemm_g <<<gg, 256, 0, stream>>>(feat, W1, G);
    gemm_ag<<<ga, 256, 0, stream>>>(A, G, c, P);
    reduce_p<<<gr, 256, 0, stream>>>(P, H1);
    // Layer 2
    gemm_g <<<gg, 256, 0, stream>>>(H1, W2, G);
    gemm_ag<<<ga, 256, 0, stream>>>(A, G, c, P);
    reduce_p<<<gr, 256, 0, stream>>>(P, H2);
    // Scoring
    score_k<<<BQ / 4, 256, 0, stream>>>(H2, relm, e1, rel, e2, out);
}